// Round 5
// baseline (197.888 us; speedup 1.0000x reference)
//
#include <hip/hip_runtime.h>
#include <math.h>

#define FHH 16
#define FWW 44
#define DB 41
#define NCAM 6
#define CIN 512
#define NC 128
#define NPIX (FHH*FWW)            // 704
#define TOTPIX (NCAM*NPIX)        // 4224
#define NPTS (NCAM*DB*NPIX)       // 173184
#define NSPAT (128*128)           // 16384
#define CHUNK 128
#define MOUT 169                  // 41 depth + 128 context
#define PARTSZ (NCAM*MOUT*NPIX)   // 713856 per k-split
#define NS 4                      // counter shards (wave-in-block)

// workspace float offsets. Zero region [cnt4 | cnt2_4 | tmp] is one memset.
#define OFF_CNT    0                          // NSPAT*NS   = 65536
#define OFF_CNT2   (NSPAT*NS)                 // 65536
#define OFF_TMP    (2*NSPAT*NS)               // 131072 ; NSPAT*NC = 2097152
#define ZERO_FLOATS (2*NSPAT*NS + NSPAT*NC)   // 2228224
#define OFF_OFFS   ZERO_FLOATS                // NSPAT*NS+1 ints, pad 16
#define OFF_BINS   (OFF_OFFS + NSPAT*NS + 16) // 2293776 ; +173184
#define OFF_PLIST  (OFF_BINS + NPTS)          // 2466960
#define OFF_WLIST  (OFF_PLIST + NPTS)         // 2640144
#define OFF_PART   (OFF_WLIST + NPTS)         // 2813328 ; +2855424
#define OFF_FEATD  (OFF_PART + 4*PARTSZ)      // 5668752 ; +173184
#define OFF_CFEATT (OFF_FEATD + NCAM*DB*NPIX) // 5841936 ; +540672 -> 6382608 floats (~25.5MB)

// ---- exact fp32 LAPACK-emulating 3x3 inverse (sgetf2 + strti2 + sgetri) ----
__device__ void lapack_inv3(const float* src, float* dst) {
    float A[3][3]; int piv[3];
    for (int i = 0; i < 3; i++)
        for (int j = 0; j < 3; j++) A[i][j] = src[i*3+j];
    for (int j = 0; j < 3; j++) {
        int p = j; float mx = fabsf(A[j][j]);
        for (int i = j+1; i < 3; i++) { float v = fabsf(A[i][j]); if (v > mx) { mx = v; p = i; } }
        piv[j] = p;
        if (p != j) for (int k = 0; k < 3; k++) { float t = A[j][k]; A[j][k] = A[p][k]; A[p][k] = t; }
        float r = __fdiv_rn(1.0f, A[j][j]);
        for (int i = j+1; i < 3; i++) A[i][j] = __fmul_rn(A[i][j], r);
        for (int i = j+1; i < 3; i++)
            for (int k = j+1; k < 3; k++)
                A[i][k] = __fsub_rn(A[i][k], __fmul_rn(A[i][j], A[j][k]));
    }
    for (int j = 0; j < 3; j++) {
        float ajj = __fdiv_rn(1.0f, A[j][j]);
        A[j][j] = ajj;
        float najj = -ajj;
        for (int k = 0; k < j; k++) {
            float temp = A[k][j];
            for (int i = 0; i < k; i++) A[i][j] = __fadd_rn(A[i][j], __fmul_rn(temp, A[i][k]));
            A[k][j] = __fmul_rn(temp, A[k][k]);
        }
        for (int i = 0; i < j; i++) A[i][j] = __fmul_rn(A[i][j], najj);
    }
    float work[3];
    for (int j = 2; j >= 0; j--) {
        for (int i = j+1; i < 3; i++) { work[i] = A[i][j]; A[i][j] = 0.0f; }
        for (int k = j+1; k < 3; k++) {
            float t = -work[k];
            for (int i = 0; i < 3; i++) A[i][j] = __fadd_rn(A[i][j], __fmul_rn(t, A[i][k]));
        }
    }
    for (int j = 2; j >= 0; j--) {
        int p = piv[j];
        if (p != j) for (int i = 0; i < 3; i++) { float t = A[i][j]; A[i][j] = A[i][p]; A[i][p] = t; }
    }
    for (int i = 0; i < 3; i++)
        for (int j = 0; j < 3; j++) dst[i*3+j] = A[i][j];
}

// ---- per-point voxel bin (exact fp32 replica) + inline matrix prep + sharded count ----
__global__ __launch_bounds__(256) void bins_kernel(const float* __restrict__ rots,
                                                   const float* __restrict__ intrins,
                                                   const float* __restrict__ post_rots,
                                                   const float* __restrict__ trans,
                                                   const float* __restrict__ post_trans,
                                                   int* __restrict__ bins,
                                                   int* __restrict__ cnt4) {
    __shared__ float sM[NCAM*9], sP[NCAM*9], sT[NCAM*3], sPT[NCAM*3];
    if (threadIdx.x < NCAM) {
        int nn = threadIdx.x;
        float invK[9], invP[9];
        lapack_inv3(intrins + nn*9, invK);
        lapack_inv3(post_rots + nn*9, invP);
        for (int i = 0; i < 3; i++)
            for (int k = 0; k < 3; k++) {
                float s = __fmul_rn(rots[nn*9 + i*3 + 0], invK[0*3 + k]);
                s = __fadd_rn(s, __fmul_rn(rots[nn*9 + i*3 + 1], invK[1*3 + k]));
                s = __fadd_rn(s, __fmul_rn(rots[nn*9 + i*3 + 2], invK[2*3 + k]));
                sM[nn*9 + i*3 + k] = s;
            }
        for (int i = 0; i < 9; i++) sP[nn*9 + i] = invP[i];
        for (int i = 0; i < 3; i++) { sT[nn*3 + i] = trans[nn*3 + i]; sPT[nn*3 + i] = post_trans[nn*3 + i]; }
    }
    __syncthreads();

    int p = blockIdx.x * 256 + threadIdx.x;
    int pc = p < NPTS ? p : NPTS - 1;
    int n   = pc / (DB*NPIX);
    int rem = pc % (DB*NPIX);
    int d   = rem / NPIX;
    int pix = rem % NPIX;
    int h = pix / FWW, w = pix % FWW;
    float xs = (float)((double)w * (703.0/43.0));
    float ys = (float)((double)h * (255.0/15.0));
    float ds = 4.0f + (float)d;
    const float* M = sM + n*9;
    const float* P = sP + n*9;
    float px = __fsub_rn(xs, sPT[n*3+0]);
    float py = __fsub_rn(ys, sPT[n*3+1]);
    float pz = __fsub_rn(ds, sPT[n*3+2]);
    float q0 = __fadd_rn(__fadd_rn(__fmul_rn(P[0],px), __fmul_rn(P[1],py)), __fmul_rn(P[2],pz));
    float q1 = __fadd_rn(__fadd_rn(__fmul_rn(P[3],px), __fmul_rn(P[4],py)), __fmul_rn(P[5],pz));
    float q2 = __fadd_rn(__fadd_rn(__fmul_rn(P[6],px), __fmul_rn(P[7],py)), __fmul_rn(P[8],pz));
    float r0 = __fmul_rn(q0, q2);
    float r1 = __fmul_rn(q1, q2);
    float r2 = q2;
    float g0 = __fadd_rn(__fadd_rn(__fadd_rn(__fmul_rn(M[0],r0), __fmul_rn(M[1],r1)), __fmul_rn(M[2],r2)), sT[n*3+0]);
    float g1 = __fadd_rn(__fadd_rn(__fadd_rn(__fmul_rn(M[3],r0), __fmul_rn(M[4],r1)), __fmul_rn(M[5],r2)), sT[n*3+1]);
    float g2 = __fadd_rn(__fadd_rn(__fadd_rn(__fmul_rn(M[6],r0), __fmul_rn(M[7],r1)), __fmul_rn(M[8],r2)), sT[n*3+2]);
    const float lox = -50.8f - (0.8f/2.0f);
    const float loy = -50.8f - (0.8f/2.0f);
    const float loz =   0.0f - (20.0f/2.0f);
    int gx = (int)(__fdiv_rn(__fsub_rn(g0, lox), 0.8f));
    int gy = (int)(__fdiv_rn(__fsub_rn(g1, loy), 0.8f));
    int gz = (int)(__fdiv_rn(__fsub_rn(g2, loz), 20.0f));
    bool ok = (gx >= 0) & (gx < 128) & (gy >= 0) & (gy < 128) & (gz >= 0) & (gz < 1);
    int s = ok ? (gy*128 + gx) : -1;
    if (p < NPTS) bins[p] = s;
    bool valid = (p < NPTS) && (s >= 0);
    int lane = threadIdx.x & 63;
    int shard = (threadIdx.x >> 6) & (NS - 1);   // MUST match fill_kernel
    unsigned long long todo = __ballot(valid);
    while (todo) {
        int lead = __builtin_ctzll(todo);
        int ls = __shfl(s, lead);
        unsigned long long match = __ballot(valid && (s == ls));
        if (valid && (s == ls)) {
            unsigned long long ltmask = (1ull << lane) - 1ull;
            int rank = __popcll(match & ltmask);
            if (rank == 0) atomicAdd(&cnt4[ls*NS + shard], __popcll(match));
        }
        todo &= ~match;
    }
}

// ---- register-tiled GEMM, K-split x4, coalesced float4 partial stores ----
#define KT 16
__global__ __launch_bounds__(256) void feat_part(const float* __restrict__ x,
                                                 const float* __restrict__ wd,
                                                 float* __restrict__ part) {
    __shared__ float xsm[KT][64];
    __shared__ float wt[KT][64];
    int n   = blockIdx.z >> 2;
    int ksp = blockIdx.z & 3;
    int o0 = blockIdx.y * 64;
    int p0 = blockIdx.x * 64;
    int tid = threadIdx.x;
    int tx = tid & 15;
    int ty = tid >> 4;
    const float* xbase = x + (size_t)n * CIN * NPIX + p0;

    int lk  = tid >> 4;
    int px4 = (tid & 15) * 4;
    int lo  = tid & 63;
    int lkq = tid >> 6;
    int orow = min(o0 + lo, MOUT - 1);

    float acc[4][4];
    #pragma unroll
    for (int i = 0; i < 4; i++)
        #pragma unroll
        for (int j = 0; j < 4; j++) acc[i][j] = 0.0f;

    int cbeg = ksp * 128;
    for (int c0 = cbeg; c0 < cbeg + 128; c0 += KT) {
        float4 xv = *(const float4*)(xbase + (size_t)(c0 + lk) * NPIX + px4);
        float4 wv = *(const float4*)(wd + (size_t)orow * CIN + c0 + lkq * 4);
        *(float4*)&xsm[lk][px4] = xv;
        wt[lkq*4 + 0][lo] = wv.x;
        wt[lkq*4 + 1][lo] = wv.y;
        wt[lkq*4 + 2][lo] = wv.z;
        wt[lkq*4 + 3][lo] = wv.w;
        __syncthreads();
        #pragma unroll
        for (int k = 0; k < KT; k++) {
            float4 a = *(const float4*)&xsm[k][tx*4];
            float4 b = *(const float4*)&wt[k][ty*4];
            acc[0][0] = fmaf(b.x, a.x, acc[0][0]);
            acc[0][1] = fmaf(b.x, a.y, acc[0][1]);
            acc[0][2] = fmaf(b.x, a.z, acc[0][2]);
            acc[0][3] = fmaf(b.x, a.w, acc[0][3]);
            acc[1][0] = fmaf(b.y, a.x, acc[1][0]);
            acc[1][1] = fmaf(b.y, a.y, acc[1][1]);
            acc[1][2] = fmaf(b.y, a.z, acc[1][2]);
            acc[1][3] = fmaf(b.y, a.w, acc[1][3]);
            acc[2][0] = fmaf(b.z, a.x, acc[2][0]);
            acc[2][1] = fmaf(b.z, a.y, acc[2][1]);
            acc[2][2] = fmaf(b.z, a.z, acc[2][2]);
            acc[2][3] = fmaf(b.z, a.w, acc[2][3]);
            acc[3][0] = fmaf(b.w, a.x, acc[3][0]);
            acc[3][1] = fmaf(b.w, a.y, acc[3][1]);
            acc[3][2] = fmaf(b.w, a.z, acc[3][2]);
            acc[3][3] = fmaf(b.w, a.w, acc[3][3]);
        }
        __syncthreads();
    }

    float* pb = part + ((size_t)(ksp * NCAM + n) * MOUT) * NPIX + p0 + tx*4;
    #pragma unroll
    for (int i = 0; i < 4; i++) {
        int o = ty*4 + i + o0;
        if (o >= MOUT) continue;
        float4 v = make_float4(acc[i][0], acc[i][1], acc[i][2], acc[i][3]);
        *(float4*)(pb + (size_t)o * NPIX) = v;
    }
}

// ---- fuse: reduce 4 partials + bias, softmax depth bins, transpose context ----
#define RPIX 32
__global__ __launch_bounds__(128) void fuse_kernel(const float* __restrict__ part,
                                                   const float* __restrict__ bd,
                                                   float* __restrict__ featd,
                                                   float* __restrict__ cfeatT) {
    __shared__ float red[8][RPIX];
    __shared__ float ctile[RPIX][129];
    int px = threadIdx.x & 31;
    int ty = threadIdx.x >> 5;
    int gpix = blockIdx.x * RPIX + px;
    int n  = gpix / NPIX;
    int pp = gpix % NPIX;
    const float* pbase = part + ((size_t)n * MOUT) * NPIX + pp;

    float v[43];
    #pragma unroll
    for (int i = 0; i < 43; i++) {
        int o = ty + 4*i;
        if (o < MOUT) {
            const float* p = pbase + (size_t)o * NPIX;
            float s = __fadd_rn(__fadd_rn(__fadd_rn(p[0], p[PARTSZ]), p[2*PARTSZ]), p[3*PARTSZ]);
            v[i] = __fadd_rn(s, bd[o]);
        }
    }
    float pmax = -1e30f;
    #pragma unroll
    for (int i = 0; i < 43; i++) { int o = ty + 4*i; if (o < DB) pmax = fmaxf(pmax, v[i]); }
    red[ty][px] = pmax;
    __syncthreads();
    float m = fmaxf(fmaxf(red[0][px], red[1][px]), fmaxf(red[2][px], red[3][px]));
    float psum = 0.0f;
    #pragma unroll
    for (int i = 0; i < 43; i++) {
        int o = ty + 4*i;
        if (o < DB) { v[i] = expf(v[i] - m); psum += v[i]; }
    }
    red[4 + ty][px] = psum;
    __syncthreads();
    float tot = __fadd_rn(__fadd_rn(__fadd_rn(red[4][px], red[5][px]), red[6][px]), red[7][px]);
    float inv = __fdiv_rn(1.0f, tot);
    #pragma unroll
    for (int i = 0; i < 43; i++) {
        int o = ty + 4*i;
        if (o < DB)        featd[((size_t)n * DB + o) * NPIX + pp] = __fmul_rn(v[i], inv);
        else if (o < MOUT) ctile[px][o - DB] = v[i];
    }
    __syncthreads();
    int pixbase = blockIdx.x * RPIX;
    #pragma unroll
    for (int r = 0; r < 32; r++) {
        int idx = threadIdx.x + 128 * r;
        int row = idx >> 7;
        int c   = idx & 127;
        cfeatT[(size_t)(pixbase + row) * NC + c] = ctile[row][c];
    }
}

// ---- exclusive prefix over NSPAT*NS sharded counts (single block, re-read) ----
__global__ __launch_bounds__(1024) void scan_kernel(const int* __restrict__ cnt4, int* __restrict__ offs) {
    __shared__ int sums[1024];
    const int PER = (NSPAT * NS) / 1024;   // 64
    int t = threadIdx.x;
    int base_i = t * PER;
    int run = 0;
    for (int i = 0; i < PER; i++) run += cnt4[base_i + i];
    sums[t] = run;
    __syncthreads();
    for (int off = 1; off < 1024; off <<= 1) {
        int u = (t >= off) ? sums[t - off] : 0;
        __syncthreads();
        sums[t] += u;
        __syncthreads();
    }
    int base = (t == 0) ? 0 : sums[t - 1];
    for (int i = 0; i < PER; i++) { offs[base_i + i] = base; base += cnt4[base_i + i]; }
    if (t == 1023) offs[NSPAT * NS] = base;
}

// ---- fill per-voxel point lists; wave-aggregated + sharded position atomics ----
__global__ __launch_bounds__(256) void fill_kernel(const int* __restrict__ bins,
                                                   const float* __restrict__ featd,
                                                   const int* __restrict__ offs, int* __restrict__ cnt2,
                                                   int* __restrict__ plist, float* __restrict__ wlist) {
    int p = blockIdx.x * 256 + threadIdx.x;
    int pc = p < NPTS ? p : NPTS - 1;
    int s = bins[pc];
    bool valid = (p < NPTS) && (s >= 0);
    int n   = pc / (DB*NPIX);
    int rem = pc % (DB*NPIX);
    int d   = rem / NPIX;
    int pix = rem % NPIX;
    int lane = threadIdx.x & 63;
    int shard = (threadIdx.x >> 6) & (NS - 1);   // MUST match bins_kernel
    int pos = 0;
    unsigned long long todo = __ballot(valid);
    while (todo) {
        int lead = __builtin_ctzll(todo);
        int ls = __shfl(s, lead);
        unsigned long long match = __ballot(valid && (s == ls));
        if (valid && (s == ls)) {
            unsigned long long ltmask = (1ull << lane) - 1ull;
            int rank = __popcll(match & ltmask);
            int basep = 0;
            if (rank == 0) basep = atomicAdd(&cnt2[ls*NS + shard], __popcll(match));
            basep = __shfl(basep, lead);
            pos = offs[ls*NS + shard] + basep + rank;
        }
        todo &= ~match;
    }
    if (valid) {
        float w = featd[((size_t)n * DB + d) * NPIX + pix];
        plist[pos] = (s << 13) | (n * NPIX + pix);
        wlist[pos] = w;
    }
}

// ---- load-balanced chunked gather: one block per 128-point chunk ----
__global__ __launch_bounds__(128) void gather_kernel(const int* __restrict__ offs,
                                                     const int* __restrict__ plist,
                                                     const float* __restrict__ wlist,
                                                     const float* __restrict__ cfeatT,
                                                     float* __restrict__ tmp) {
    __shared__ int keys[CHUNK];
    __shared__ float wts[CHUNK];
    int T = offs[NSPAT * NS];
    int base = blockIdx.x * CHUNK;
    if (base >= T) return;
    int end = min(base + CHUNK, T);
    int m = end - base;
    int c = threadIdx.x;
    if (c < m) { keys[c] = plist[base + c]; wts[c] = wlist[base + c]; }
    __syncthreads();
    float acc = 0.0f;
    int cur = keys[0] >> 13;
    for (int i = 0; i < m; i++) {
        int key = keys[i];
        int s = key >> 13;
        if (s != cur) {
            bool span = (offs[cur*NS] < base) || (offs[cur*NS + NS] > end);
            if (span) atomicAdd(&tmp[(size_t)cur * NC + c], acc);
            else      tmp[(size_t)cur * NC + c] = acc;
            acc = 0.0f;
            cur = s;
        }
        acc = fmaf(wts[i], cfeatT[(size_t)(key & 0x1FFF) * NC + c], acc);
    }
    bool span = (offs[cur*NS] < base) || (offs[cur*NS + NS] > end);
    if (span) atomicAdd(&tmp[(size_t)cur * NC + c], acc);
    else      tmp[(size_t)cur * NC + c] = acc;
}

// ---- transpose tmp[s][c] -> out[c][s] ----
__global__ void transpose_kernel(const float* __restrict__ tmp, float* __restrict__ out) {
    __shared__ float tile[32][33];
    int s0 = blockIdx.x * 32;
    int c0 = blockIdx.y * 32;
    int tx = threadIdx.x;
    int ty = threadIdx.y;
    #pragma unroll
    for (int i = 0; i < 32; i += 8)
        tile[ty + i][tx] = tmp[(size_t)(s0 + ty + i) * NC + c0 + tx];
    __syncthreads();
    #pragma unroll
    for (int i = 0; i < 32; i += 8)
        out[(size_t)(c0 + ty + i) * NSPAT + s0 + tx] = tile[tx][ty + i];
}

extern "C" void kernel_launch(void* const* d_in, const int* in_sizes, int n_in,
                              void* d_out, int out_size, void* d_ws, size_t ws_size,
                              hipStream_t stream) {
    const float* x          = (const float*)d_in[0];
    const float* rots       = (const float*)d_in[1];
    const float* trans      = (const float*)d_in[2];
    const float* intrins    = (const float*)d_in[3];
    const float* post_rots  = (const float*)d_in[4];
    const float* post_trans = (const float*)d_in[5];
    const float* w_depth    = (const float*)d_in[6];
    const float* b_depth    = (const float*)d_in[7];
    float* out = (float*)d_out;
    float* ws  = (float*)d_ws;

    int*   cnt4    = (int*)(ws + OFF_CNT);
    int*   cnt2    = (int*)(ws + OFF_CNT2);
    float* tmp     = ws + OFF_TMP;
    int*   offs    = (int*)(ws + OFF_OFFS);
    int*   bins    = (int*)(ws + OFF_BINS);
    int*   plist   = (int*)(ws + OFF_PLIST);
    float* wlist   = ws + OFF_WLIST;
    float* part    = ws + OFF_PART;
    float* featd   = ws + OFF_FEATD;
    float* cfeatT  = ws + OFF_CFEATT;

    // one memset zeroes cnt4 + cnt2 + tmp (contiguous)
    hipMemsetAsync(ws, 0, (size_t)ZERO_FLOATS * sizeof(float), stream);
    bins_kernel<<<(NPTS + 255) / 256, 256, 0, stream>>>(rots, intrins, post_rots, trans, post_trans, bins, cnt4);
    feat_part<<<dim3(11, 3, NCAM * 4), 256, 0, stream>>>(x, w_depth, part);
    scan_kernel<<<1, 1024, 0, stream>>>(cnt4, offs);
    fuse_kernel<<<TOTPIX / RPIX, 128, 0, stream>>>(part, b_depth, featd, cfeatT);
    fill_kernel<<<(NPTS + 255) / 256, 256, 0, stream>>>(bins, featd, offs, cnt2, plist, wlist);
    gather_kernel<<<(NPTS + CHUNK - 1) / CHUNK, 128, 0, stream>>>(offs, plist, wlist, cfeatT, tmp);
    transpose_kernel<<<dim3(NSPAT / 32, NC / 32), dim3(32, 8), 0, stream>>>(tmp, out);
}